// Round 7
// baseline (166.898 us; speedup 1.0000x reference)
//
#include <hip/hip_runtime.h>
#include <hip/hip_bf16.h>

constexpr int NB = 8;      // batch
constexpr int T  = 2048;   // seq
constexpr int C  = 1024;   // embed
constexpr int Hd = 128;    // head size

typedef short bf16x8 __attribute__((ext_vector_type(8)));
typedef float floatx4 __attribute__((ext_vector_type(4)));

__device__ __forceinline__ ushort f2bf(float x) {
    return __builtin_bit_cast(ushort, __float2bfloat16(x));
}
__device__ __forceinline__ float bf2f(ushort u) {
    unsigned int x = ((unsigned int)u) << 16;
    return __builtin_bit_cast(float, x);
}
__device__ __forceinline__ unsigned pk2(float a, float b) {
    return ((unsigned)f2bf(a)) | (((unsigned)f2bf(b)) << 16);
}
__device__ __forceinline__ void async16(ushort* lds, const ushort* g) {
    __builtin_amdgcn_global_load_lds(
        (const __attribute__((address_space(1))) unsigned int*)g,
        (__attribute__((address_space(3))) unsigned int*)lds, 16, 0, 0);
}

// ---------------------------------------------------------------------------
// Kernel 1: fused fp32->bf16 convert for X and stacked W (Wq scaled).
// ---------------------------------------------------------------------------
__global__ __launch_bounds__(256) void convert_xw(
    const float* __restrict__ X, const float* __restrict__ Wq,
    const float* __restrict__ Wk, const float* __restrict__ Wv,
    ushort* __restrict__ Xb, ushort* __restrict__ Wb)
{
    int bid = blockIdx.x;
    if (bid < 8192) {
        size_t i = ((size_t)bid * 256 + threadIdx.x) * 8;
        float4 a = *(const float4*)&X[i];
        float4 b = *(const float4*)&X[i + 4];
        bf16x8 o;
        o[0] = (short)f2bf(a.x); o[1] = (short)f2bf(a.y);
        o[2] = (short)f2bf(a.z); o[3] = (short)f2bf(a.w);
        o[4] = (short)f2bf(b.x); o[5] = (short)f2bf(b.y);
        o[6] = (short)f2bf(b.z); o[7] = (short)f2bf(b.w);
        *(bf16x8*)&Xb[i] = o;
    } else {
        int g = (bid - 8192) * 256 + threadIdx.x;
        size_t base = (size_t)g * 8;
        int sel = (int)(base >> 17);
        const float* W = sel == 0 ? Wq : (sel == 1 ? Wk : Wv);
        float s = (sel == 0) ? 0.12751744f : 1.0f;     // log2e/sqrt(128) in Wq
        size_t off = base - (size_t)sel * 131072;
        float4 a = *(const float4*)&W[off];
        float4 b = *(const float4*)&W[off + 4];
        bf16x8 o;
        o[0] = (short)f2bf(a.x * s); o[1] = (short)f2bf(a.y * s);
        o[2] = (short)f2bf(a.z * s); o[3] = (short)f2bf(a.w * s);
        o[4] = (short)f2bf(b.x * s); o[5] = (short)f2bf(b.y * s);
        o[6] = (short)f2bf(b.z * s); o[7] = (short)f2bf(b.w * s);
        *(bf16x8*)&Wb[base] = o;
    }
}

// ---------------------------------------------------------------------------
// Kernel 2: QKV GEMM bf16, BM=128 BN=64 BK=64, global_load_lds + XOR swizzle.
// SWAPPED operands: accT = mfma(W_frag, X_frag) = D^T [h][row] -> each lane
// holds 4 consecutive h -> packed dwordx2 epilogue stores.
// V blocks: packed LDS transpose -> Vt[b][h][t].
// ---------------------------------------------------------------------------
__global__ __launch_bounds__(256) void qkv_gemm(
    const ushort* __restrict__ Xb, const ushort* __restrict__ Wb,
    ushort* __restrict__ Qo, ushort* __restrict__ Ko, ushort* __restrict__ Vt)
{
    __shared__ ushort SM[12288];          // 24KB: Al(8192) + Bl(4096); TL overlays
    ushort* Al = SM;                      // 128x64
    ushort* Bl = SM + 8192;               // 64x64
    const int m0 = blockIdx.x * 128;
    const int n0 = blockIdx.y * 64;       // row into stacked Wb [384][1024]
    const int tid = threadIdx.x, lane = tid & 63, wave = tid >> 6;
    const int quad = lane >> 4, colL = lane & 15;
    const int wm = (wave & 1) * 64, wn = (wave >> 1) * 32;
    const int lr = lane >> 3;
    const int lcs = ((lane & 7) ^ (lr & 7)) * 8;   // swizzled source column

    floatx4 accT[2][4] = {};              // [h-tile][row-tile] (D^T)

    for (int k0 = 0; k0 < C; k0 += 64) {
        for (int t = 0; t < 4; ++t) {
            int q = wave * 4 + t;                   // 16 chunks (A: 128x64)
            async16(&Al[q * 512 + lane * 8],
                    &Xb[(size_t)(m0 + q * 8 + lr) * C + k0 + lcs]);
        }
        for (int t = 0; t < 2; ++t) {
            int q = wave * 2 + t;                   // 8 chunks (B: 64x64)
            async16(&Bl[q * 512 + lane * 8],
                    &Wb[(size_t)(n0 + q * 8 + lr) * C + k0 + lcs]);
        }
        __syncthreads();

        bf16x8 af[2][4], bfr[2][2];
        for (int kk = 0; kk < 2; ++kk) {
            for (int mt = 0; mt < 4; ++mt)
                af[kk][mt] = *(const bf16x8*)
                    &Al[(wm + mt * 16 + colL) * 64 + (((kk * 4 + quad) ^ (colL & 7))) * 8];
            for (int nt = 0; nt < 2; ++nt)
                bfr[kk][nt] = *(const bf16x8*)
                    &Bl[(wn + nt * 16 + colL) * 64 + (((kk * 4 + quad) ^ (colL & 7))) * 8];
        }
        for (int kk = 0; kk < 2; ++kk)
            for (int nt = 0; nt < 2; ++nt)
                for (int mt = 0; mt < 4; ++mt)
                    accT[nt][mt] = __builtin_amdgcn_mfma_f32_16x16x32_bf16(
                        bfr[kk][nt], af[kk][mt], accT[nt][mt], 0, 0, 0);
        __syncthreads();
    }

    const int sel = n0 >> 7;              // 0,0,1,1,2,2
    const int h0 = n0 & 127;              // 0 or 64
    if (sel < 2) {
        ushort* dst = sel == 0 ? Qo : Ko;
        for (int nt = 0; nt < 2; ++nt)
            for (int mt = 0; mt < 4; ++mt) {
                int row = m0 + wm + mt * 16 + colL;
                int h = h0 + wn + nt * 16 + quad * 4;
                uint2 pk;
                pk.x = pk2(accT[nt][mt][0], accT[nt][mt][1]);
                pk.y = pk2(accT[nt][mt][2], accT[nt][mt][3]);
                *(uint2*)&dst[(size_t)row * Hd + h] = pk;
            }
    } else {
        // V: packed transpose through TL[t 128][h 64, pad 68]
        ushort* TL = SM;                  // 8704 ushorts, overlays Al/Bl
        for (int nt = 0; nt < 2; ++nt)
            for (int mt = 0; mt < 4; ++mt) {
                int t = wm + mt * 16 + colL;
                int h = wn + nt * 16 + quad * 4;
                uint2 pk;
                pk.x = pk2(accT[nt][mt][0], accT[nt][mt][1]);
                pk.y = pk2(accT[nt][mt][2], accT[nt][mt][3]);
                *(uint2*)&TL[t * 68 + h] = pk;
            }
        __syncthreads();
        const int b = m0 >> 11, tb = m0 & 2047;
        const int h = tid & 63, tq = tid >> 6;     // thread: h col, 32-t strip
        for (int st = 0; st < 4; ++st) {
            int t0 = tq * 32 + st * 8;
            bf16x8 o;
            for (int jx = 0; jx < 8; ++jx)
                o[jx] = (short)TL[(t0 + jx) * 68 + h];
            *(bf16x8*)&Vt[((size_t)b * Hd + h0 + h) * T + tb + t0] = o;
        }
    }
}

// ---------------------------------------------------------------------------
// Kernel 3: split-K causal flash attention, transposed-MFMA form.
// Block = (b, qblock j of 128 rows, kchunk c of 128 keys), c <= j. 4 waves,
// wave owns 32 q (2 groups of 16). S^T = mfma(K,Q); O^T = mfma(V,P).
// P: per-wave dedicated 4KB LDS, key-halved -> packed b64 writes, b128 reads.
// LDS 80KB total (Kl 32 + Vl 32 + Pl 16) -> 2 blocks/CU, ONE barrier.
// ---------------------------------------------------------------------------
__global__ __launch_bounds__(256, 2) void attn_partial(
    const ushort* __restrict__ Q, const ushort* __restrict__ Kg,
    const ushort* __restrict__ Vt, ushort* __restrict__ Opart,
    float* __restrict__ mpart, float* __restrict__ lpart)
{
    __shared__ ushort Kl[128 * 128];   // 32KB [key][h] swizzled
    __shared__ ushort Vl[128 * 128];   // 32KB [h][key] swizzled
    __shared__ ushort Pl[4][2048];     // 4KB/wave: [32 q][64 keys] chunk-swizzled

    const int tid = threadIdx.x, lane = tid & 63, wave = tid >> 6;
    const int quad = lane >> 4, colL = lane & 15;

    int id = blockIdx.x;               // 0..1087, heavy-first decode
    int b = id / 136;
    int rem = id - b * 136;
    int j = 15;
    while (rem >= j + 1) { rem -= (j + 1); --j; }
    int c = rem;
    const int q0 = j * 128;
    const int k0 = c * 128;
    const bool diag = (c == j);

    {
        int r = tid >> 4, p = tid & 15;
        for (int t = 0; t < 8; ++t) {
            int row = t * 16 + r;
            async16(&Kl[t * 2048 + tid * 8],
                    &Kg[((size_t)b * T + k0 + row) * Hd + ((p ^ (row & 15)) * 8)]);
        }
        for (int t = 0; t < 8; ++t) {
            int hrow = t * 16 + r;
            async16(&Vl[t * 2048 + tid * 8],
                    &Vt[((size_t)b * Hd + hrow) * T + k0 + ((p ^ (hrow & 15)) * 8)]);
        }
    }

    // Q frags (B-operand: n = q = colL), 2 q-groups of 16
    bf16x8 qa[2][4];
    for (int qg = 0; qg < 2; ++qg) {
        const ushort* qp =
            &Q[((size_t)b * T + q0 + wave * 32 + qg * 16 + colL) * Hd + quad * 8];
        for (int ks = 0; ks < 4; ++ks)
            qa[qg][ks] = *(const bf16x8*)&qp[ks * 32];
    }

    __syncthreads();   // the only barrier: staging drained

    // S^T = K Q^T : accST[qg][key-tile], D[m=key][n=q]
    floatx4 accST[2][8] = {};
    for (int ks = 0; ks < 4; ++ks)
        for (int kt = 0; kt < 8; ++kt) {
            bf16x8 kb = *(const bf16x8*)
                &Kl[(kt * 16 + colL) * 128 + (((ks * 4 + quad) ^ colL) * 8)];
            accST[0][kt] = __builtin_amdgcn_mfma_f32_16x16x32_bf16(
                kb, qa[0][ks], accST[0][kt], 0, 0, 0);
            accST[1][kt] = __builtin_amdgcn_mfma_f32_16x16x32_bf16(
                kb, qa[1][ks], accST[1][kt], 0, 0, 0);
        }

    if (diag) {
        for (int qg = 0; qg < 2; ++qg) {
            int qglob = q0 + wave * 32 + qg * 16 + colL;
            for (int kt = 0; kt < 8; ++kt)
                for (int rr = 0; rr < 4; ++rr) {
                    int keyg = k0 + kt * 16 + quad * 4 + rr;
                    if (keyg > qglob) accST[qg][kt][rr] = -__builtin_inff();
                }
        }
    }

    // row max: in-lane over 32 values + 2 cross-quad shfls
    float m_r[2], l_r[2];
    for (int qg = 0; qg < 2; ++qg) {
        float mx = accST[qg][0][0];
        for (int kt = 0; kt < 8; ++kt)
            for (int rr = 0; rr < 4; ++rr)
                mx = fmaxf(mx, accST[qg][kt][rr]);
        mx = fmaxf(mx, __shfl_xor(mx, 16, 64));
        mx = fmaxf(mx, __shfl_xor(mx, 32, 64));
        m_r[qg] = mx;
        l_r[qg] = 0.f;
    }

    ushort* Plw = Pl[wave];
    floatx4 OaccT[2][8] = {};
    for (int kh = 0; kh < 2; ++kh) {
        // write P key-half (packed b64: 4 consecutive keys per lane)
        for (int qg = 0; qg < 2; ++qg) {
            int q = qg * 16 + colL;
            for (int ktl = 0; ktl < 4; ++ktl) {
                floatx4 sv = accST[qg][kh * 4 + ktl];
                float p0 = __builtin_amdgcn_exp2f(sv[0] - m_r[qg]);
                float p1 = __builtin_amdgcn_exp2f(sv[1] - m_r[qg]);
                float p2 = __builtin_amdgcn_exp2f(sv[2] - m_r[qg]);
                float p3 = __builtin_amdgcn_exp2f(sv[3] - m_r[qg]);
                l_r[qg] += (p0 + p1) + (p2 + p3);
                int chunk = ktl * 2 + (quad >> 1);
                uint2 pk;
                pk.x = pk2(p0, p1);
                pk.y = pk2(p2, p3);
                *(uint2*)&Plw[q * 64 + ((chunk ^ (q & 7)) * 8) + (quad & 1) * 4] = pk;
            }
        }
        // O^T += V * P for this half (same-wave LDS, lgkmcnt only)
        for (int ksl = 0; ksl < 2; ++ksl) {
            int ks = kh * 2 + ksl;
            bf16x8 pf[2];
            for (int qg = 0; qg < 2; ++qg) {
                int q = qg * 16 + colL;
                pf[qg] = *(const bf16x8*)
                    &Plw[q * 64 + (((ksl * 4 + quad) ^ (q & 7)) * 8)];
            }
            for (int mh = 0; mh < 8; ++mh) {
                bf16x8 vb = *(const bf16x8*)
                    &Vl[(mh * 16 + colL) * 128 + (((ks * 4 + quad) ^ colL) * 8)];
                OaccT[0][mh] = __builtin_amdgcn_mfma_f32_16x16x32_bf16(
                    vb, pf[0], OaccT[0][mh], 0, 0, 0);
                OaccT[1][mh] = __builtin_amdgcn_mfma_f32_16x16x32_bf16(
                    vb, pf[1], OaccT[1][mh], 0, 0, 0);
            }
        }
    }

    for (int qg = 0; qg < 2; ++qg) {
        float s = l_r[qg];
        s += __shfl_xor(s, 16, 64);
        s += __shfl_xor(s, 32, 64);
        l_r[qg] = s;
    }

    // epilogue: Opart[slot][q][h], packed dwordx2 (4 consecutive h per lane)
    const int slot = b * 136 + (j * (j + 1)) / 2 + c;
    ushort* Op = &Opart[(size_t)slot * 16384];
    for (int qg = 0; qg < 2; ++qg) {
        int q = wave * 32 + qg * 16 + colL;
        for (int mh = 0; mh < 8; ++mh) {
            uint2 pk;
            pk.x = pk2(OaccT[qg][mh][0], OaccT[qg][mh][1]);
            pk.y = pk2(OaccT[qg][mh][2], OaccT[qg][mh][3]);
            *(uint2*)&Op[q * 128 + mh * 16 + quad * 4] = pk;
        }
        if (quad == 0) {
            mpart[(size_t)slot * 128 + q] = m_r[qg];
            lpart[(size_t)slot * 128 + q] = l_r[qg];
        }
    }
}

// ---------------------------------------------------------------------------
// Kernel 4: merge partials, write fp32 out. Grid (16 j, 8 b, 4 rowquarter),
// heavy-first (j = 15 - bx). Thread owns (row, 16-h chunk).
// ---------------------------------------------------------------------------
__global__ __launch_bounds__(256) void attn_combine(
    const ushort* __restrict__ Opart, const float* __restrict__ mpart,
    const float* __restrict__ lpart, float* __restrict__ out)
{
    const int j = 15 - blockIdx.x, b = blockIdx.y;
    const int nch = j + 1;
    const int sbase = b * 136 + (j * (j + 1)) / 2;
    const int t = threadIdx.x;
    const int row = blockIdx.z * 32 + (t >> 3);
    const int h0 = (t & 7) * 16;

    float M = -__builtin_inff();
    for (int c = 0; c < nch; ++c)
        M = fmaxf(M, mpart[(size_t)(sbase + c) * 128 + row]);
    float ltot = 0.f;
    for (int c = 0; c < nch; ++c)
        ltot += lpart[(size_t)(sbase + c) * 128 + row] *
                __builtin_amdgcn_exp2f(mpart[(size_t)(sbase + c) * 128 + row] - M);

    float o[16];
    for (int i = 0; i < 16; ++i) o[i] = 0.f;
    for (int c = 0; c < nch; ++c) {
        float wgt = __builtin_amdgcn_exp2f(mpart[(size_t)(sbase + c) * 128 + row] - M);
        const ushort* Op = &Opart[(size_t)(sbase + c) * 16384 + row * 128 + h0];
        for (int x = 0; x < 2; ++x) {
            bf16x8 v = *(const bf16x8*)&Op[x * 8];
            for (int i2 = 0; i2 < 8; ++i2)
                o[x * 8 + i2] += bf2f((ushort)v[i2]) * wgt;
        }
    }
    float inv = 1.0f / ltot;
    float* dst = &out[((size_t)(b * T) + j * 128 + row) * Hd + h0];
    for (int i = 0; i < 16; ++i) dst[i] = o[i] * inv;
}

// ---------------------------------------------------------------------------
extern "C" void kernel_launch(void* const* d_in, const int* in_sizes, int n_in,
                              void* d_out, int out_size, void* d_ws, size_t ws_size,
                              hipStream_t stream) {
    const float* x  = (const float*)d_in[0];
    const float* Wq = (const float*)d_in[1];
    const float* Wk = (const float*)d_in[2];
    const float* Wv = (const float*)d_in[3];
    float* out = (float*)d_out;

    // ws (~49.4 MB). Region A time-shared: Xb+Wb live until qkv_gemm ends;
    // Opart/mpart/lpart (written later by attn_partial) alias it.
    char* w = (char*)d_ws;
    ushort* Xb = (ushort*)w;                                   // 33.55 MB
    ushort* Wb = (ushort*)(w + (size_t)33554432);              // 0.79 MB
    ushort* Opart = (ushort*)w;                                // 1088*32KB = 35.65 MB
    float* mpart = (float*)(w + (size_t)35651584);             // 0.56 MB
    float* lpart = (float*)(w + (size_t)35651584 + 557056);    // 0.56 MB
    w += (size_t)35651584 + 2 * 557056;
    ushort* Qb  = (ushort*)w;  w += (size_t)NB * T * Hd * 2;   // 4.19 MB
    ushort* Kb  = (ushort*)w;  w += (size_t)NB * T * Hd * 2;
    ushort* Vtb = (ushort*)w;  w += (size_t)NB * T * Hd * 2;

    convert_xw<<<8384, 256, 0, stream>>>(x, Wq, Wk, Wv, Xb, Wb);
    qkv_gemm<<<dim3(128, 6), 256, 0, stream>>>(Xb, Wb, Qb, Kb, Vtb);
    attn_partial<<<1088, 256, 0, stream>>>(Qb, Kb, Vtb, Opart, mpart, lpart);
    attn_combine<<<dim3(16, 8, 4), 256, 0, stream>>>(Opart, mpart, lpart, out);
}